// Round 1
// 509.513 us; speedup vs baseline: 1.1365x; 1.1365x over previous
//
#include <hip/hip_runtime.h>
#include <cstdint>
#include <cstddef>

// Problem dims (fixed by setup_inputs): B=4, S=2048, I=4096, O=4096
#define DIM_M 8192   // B*S
#define DIM_N 4096   // O
#define DIM_K 4096   // I

// GEMM tiling (8-phase 256^2 template, BK=32, 4-deep LDS ring)
#define BM 256
#define BN 256
#define BK 32
#define NT (DIM_K / BK)   // 128 K-tiles

typedef __bf16 bf16x8 __attribute__((ext_vector_type(8)));
typedef float fvec4 __attribute__((ext_vector_type(4)));
typedef int   ivec4 __attribute__((ext_vector_type(4)));
typedef unsigned int uvec4 __attribute__((ext_vector_type(4)));

__device__ __constant__ float NF4_TAB[16] = {
    -1.0f, -0.6961928009986877f, -0.5250730514526367f, -0.39491748809814453f,
    -0.28444138169288635f, -0.18477343022823334f, -0.09105003625154495f, 0.0f,
    0.07958029955625534f, 0.16093020141124725f, 0.24611230194568634f,
    0.33791524171829224f, 0.44070982933044434f, 0.5626170039176941f,
    0.7229568362236023f, 1.0f};

// float -> bf16 bits, round-to-nearest-even (finite inputs only)
__device__ inline unsigned short f2bf(float f) {
    unsigned int u = __builtin_bit_cast(unsigned int, f);
    u += 0x7fffu + ((u >> 16) & 1u);
    return (unsigned short)(u >> 16);
}

// ---------------- fused prep: x fp32->bf16  +  NF4 double-dequant ----------------
// (unchanged this round — gemm is the attributed change; prep will surface in
//  the top-5 dispatches once gemm drops below it)
__global__ void prep_kernel(const float* __restrict__ x, unsigned short* __restrict__ xb,
                            const int* __restrict__ codes,
                            const int* __restrict__ am_codes,
                            const float* __restrict__ am_scale,
                            const float* __restrict__ am_off,
                            unsigned short* __restrict__ wb,
                            int xcv_blocks) {
    if ((int)blockIdx.x < xcv_blocks) {
        size_t base = ((size_t)blockIdx.x * blockDim.x + threadIdx.x) * 8;
        fvec4 a = __builtin_nontemporal_load((const fvec4*)(x + base));
        fvec4 b = __builtin_nontemporal_load((const fvec4*)(x + base + 4));
        unsigned short r[8];
        r[0] = f2bf(a.x); r[1] = f2bf(a.y); r[2] = f2bf(a.z); r[3] = f2bf(a.w);
        r[4] = f2bf(b.x); r[5] = f2bf(b.y); r[6] = f2bf(b.z); r[7] = f2bf(b.w);
        *(uvec4*)(xb + base) = *(const uvec4*)r;
    } else {
        __shared__ float nf4[16];
        if (threadIdx.x < 16) nf4[threadIdx.x] = NF4_TAB[threadIdx.x];
        __syncthreads();
        size_t base = ((size_t)(blockIdx.x - xcv_blocks) * blockDim.x + threadIdx.x) * 8;
        int blk = (int)(base >> 6);
        float absmax = (float)am_codes[blk] * (1.0f / 255.0f) * am_scale[blk >> 8] + am_off[0];
        ivec4 c0 = __builtin_nontemporal_load((const ivec4*)(codes + base));
        ivec4 c1 = __builtin_nontemporal_load((const ivec4*)(codes + base + 4));
        unsigned short r[8];
        r[0] = f2bf(nf4[c0.x & 15] * absmax);
        r[1] = f2bf(nf4[c0.y & 15] * absmax);
        r[2] = f2bf(nf4[c0.z & 15] * absmax);
        r[3] = f2bf(nf4[c0.w & 15] * absmax);
        r[4] = f2bf(nf4[c1.x & 15] * absmax);
        r[5] = f2bf(nf4[c1.y & 15] * absmax);
        r[6] = f2bf(nf4[c1.z & 15] * absmax);
        r[7] = f2bf(nf4[c1.w & 15] * absmax);
        *(uvec4*)(wb + base) = *(const uvec4*)r;
    }
}

// ---------------- 256x256 8-phase bf16 MFMA GEMM (B^T input), counted vmcnt ----------------
//
// Structure (m201-template lineage):
//   512 threads = 8 waves (2 M x 4 N), per-wave 128x64 output, mfma 16x16x32.
//   LDS: 4-buffer ring per operand, each buf 256 rows x 32 k bf16 (16 KiB) -> 128 KiB.
//   Pipeline: tile t+3 issued (global_load_lds) during tile t's compute; at each
//   tile boundary wait vmcnt(8) (= tiles t+2,t+3 in flight) — never 0 in steady state.
//   Raw s_barrier only (NO __syncthreads: it drains vmcnt(0) and kills the pipeline).
//
// LDS swizzle (both-sides-or-neither): slot (row, c) holds global k-chunk
// c ^ ((row>>1)&3)  (chunk = 8 bf16 = 16 B).  Staging keeps the mandatory linear
// LDS destination (base + lane*16) and pre-swizzles each lane's GLOBAL source
// chunk; fragment reads apply the same XOR.  Result: each wave's 64x16B
// ds_read_b128 lands exactly 32 B on every bank — conflict-free.
__device__ inline void gld_lds16(const void* g, void* l) {
    __builtin_amdgcn_global_load_lds((__attribute__((address_space(1))) void*)g,
                                     (__attribute__((address_space(3))) void*)l,
                                     16, 0, 0);
}

__global__ __launch_bounds__(512, 2) void gemm_bt(const unsigned short* __restrict__ A,
                                                  const unsigned short* __restrict__ B,
                                                  const float* __restrict__ bias,
                                                  float* __restrict__ C,
                                                  int M, int N, int K) {
    __shared__ __attribute__((aligned(16))) unsigned short lA[4][BM * BK];
    __shared__ __attribute__((aligned(16))) unsigned short lB[4][BN * BK];

    const int tid  = threadIdx.x;
    const int wave = tid >> 6;
    const int lane = tid & 63;

    // Bijective XCD swizzle: 512 wgs, 8 XCDs. Each XCD owns bm in {xcd, xcd+8, ...}
    // and walks bn 0..15 in lockstep with the others (A panels L2-hot per XCD,
    // B panels L3-resident and shared).
    const int orig = (int)blockIdx.x;
    const int xcd = orig & 7;
    const int idx = orig >> 3;                 // 0..63
    const int bm = ((idx >> 4) << 3) + xcd;    // 0..31
    const int bn = idx & 15;                   // 0..15

    const int wr = wave >> 2;                  // 0..1 (M)
    const int wc = wave & 3;                   // 0..3 (N)
    const int wm = wr * 128;
    const int wn = wc * 64;

    // ---- staging addresses ----
    // Per operand per tile: 256 rows x 4 chunks = 1024 slots of 16 B; thread t owns
    // slots t and t+512 (rows r0 and r0+128, same chunk column).  Source chunk is
    // pre-swizzled: gch = (t&3) ^ ((t>>3)&3)  (== c ^ ((row>>1)&3) for both slots).
    const int srow = tid >> 2;                           // 0..127
    const int gch  = (tid & 3) ^ ((tid >> 3) & 3);
    const unsigned short* sA0 = A + (size_t)(bm * BM + srow) * K + gch * 8;
    const unsigned short* sA1 = sA0 + (size_t)128 * K;
    const unsigned short* sB0 = B + (size_t)(bn * BN + srow) * K + gch * 8;
    const unsigned short* sB1 = sB0 + (size_t)128 * K;

    // ---- fragment read offsets (elems) ----
    // A-frag (m): row = wm + m*16 + (lane&15), global k-chunk kc = lane>>4,
    // stored at slot chunk kc ^ ((row>>1)&3) = kc ^ ((lane>>1)&3).
    const int cslot = (lane >> 4) ^ ((lane >> 1) & 3);
    const int aoff = (wm + (lane & 15)) * BK + cslot * 8;
    const int boff = (wn + (lane & 15)) * BK + cslot * 8;

    fvec4 acc[8][4];
#pragma unroll
    for (int m = 0; m < 8; ++m)
#pragma unroll
        for (int n = 0; n < 4; ++n)
#pragma unroll
            for (int r = 0; r < 4; ++r) acc[m][n][r] = 0.0f;

    // ---- prologue: issue tiles 0,1,2 (12 loads/thread), wait tile 0 (vmcnt(8)) ----
#pragma unroll
    for (int pt = 0; pt < 3; ++pt) {
        const int kb = pt * BK;
        gld_lds16(sA0 + kb, &lA[pt][tid * 8]);
        gld_lds16(sA1 + kb, &lA[pt][(tid + 512) * 8]);
        gld_lds16(sB0 + kb, &lB[pt][tid * 8]);
        gld_lds16(sB1 + kb, &lB[pt][(tid + 512) * 8]);
    }
    asm volatile("s_waitcnt vmcnt(8)" ::: "memory");
    __builtin_amdgcn_s_barrier();

    // ---- main loop: 2 phases / K-tile, 16 MFMA each ----
    for (int t = 0; t < NT; ++t) {
        const int b = t & 3;
        const unsigned short* la = lA[b];
        const unsigned short* lb = lB[b];

        // ---- phase alpha: read A[m0..3] + B[n0..3]; issue A of tile t+3 ----
        bf16x8 a0[4], bv[4];
#pragma unroll
        for (int m = 0; m < 4; ++m) a0[m] = *(const bf16x8*)(la + aoff + m * 512);
#pragma unroll
        for (int n = 0; n < 4; ++n) bv[n] = *(const bf16x8*)(lb + boff + n * 512);
        if (t + 3 < NT) {
            const int nb = (t + 3) & 3;
            const size_t kb = (size_t)(t + 3) * BK;
            gld_lds16(sA0 + kb, &lA[nb][tid * 8]);
            gld_lds16(sA1 + kb, &lA[nb][(tid + 512) * 8]);
        }
        __builtin_amdgcn_s_barrier();
        asm volatile("s_waitcnt lgkmcnt(0)" ::: "memory");
        __builtin_amdgcn_sched_barrier(0);   // rule #18: keep MFMA below the wait
        __builtin_amdgcn_s_setprio(1);
#pragma unroll
        for (int m = 0; m < 4; ++m)
#pragma unroll
            for (int n = 0; n < 4; ++n)
                acc[m][n] = __builtin_amdgcn_mfma_f32_16x16x32_bf16(a0[m], bv[n], acc[m][n], 0, 0, 0);
        __builtin_amdgcn_s_setprio(0);
        __builtin_amdgcn_s_barrier();

        // ---- phase beta: read A[m4..7]; issue B of tile t+3 ----
        bf16x8 a1[4];
#pragma unroll
        for (int m = 0; m < 4; ++m) a1[m] = *(const bf16x8*)(la + aoff + (m + 4) * 512);
        if (t + 3 < NT) {
            const int nb = (t + 3) & 3;
            const size_t kb = (size_t)(t + 3) * BK;
            gld_lds16(sB0 + kb, &lB[nb][tid * 8]);
            gld_lds16(sB1 + kb, &lB[nb][(tid + 512) * 8]);
        }
        __builtin_amdgcn_s_barrier();
        asm volatile("s_waitcnt lgkmcnt(0)" ::: "memory");
        __builtin_amdgcn_sched_barrier(0);
        __builtin_amdgcn_s_setprio(1);
#pragma unroll
        for (int m = 0; m < 4; ++m)
#pragma unroll
            for (int n = 0; n < 4; ++n)
                acc[m + 4][n] = __builtin_amdgcn_mfma_f32_16x16x32_bf16(a1[m], bv[n], acc[m + 4][n], 0, 0, 0);
        __builtin_amdgcn_s_setprio(0);

        // ---- tile boundary: counted vmcnt (per-wave own loads) THEN barrier,
        //      so after the barrier every wave's tile-(t+1) data is in LDS ----
        if (t < NT - 3)       { asm volatile("s_waitcnt vmcnt(8)" ::: "memory"); }
        else if (t == NT - 3) { asm volatile("s_waitcnt vmcnt(4)" ::: "memory"); }
        else if (t == NT - 2) { asm volatile("s_waitcnt vmcnt(0)" ::: "memory"); }
        if (t < NT - 1) __builtin_amdgcn_s_barrier();
    }

    // ---- epilogue: C/D 16x16 layout col = lane&15, row = (lane>>4)*4 + r ----
    const int col0 = bn * BN + wn + (lane & 15);
    const int row0 = bm * BM + wm + ((lane >> 4) << 2);
#pragma unroll
    for (int n = 0; n < 4; ++n) {
        const float bvs = bias[col0 + n * 16];
#pragma unroll
        for (int m = 0; m < 8; ++m) {
            float* cp = C + (size_t)(row0 + m * 16) * N + col0 + n * 16;
#pragma unroll
            for (int r = 0; r < 4; ++r)
                __builtin_nontemporal_store(acc[m][n][r] + bvs, cp + (size_t)r * N);
        }
    }
}

extern "C" void kernel_launch(void* const* d_in, const int* in_sizes, int n_in,
                              void* d_out, int out_size, void* d_ws, size_t ws_size,
                              hipStream_t stream) {
    const float* x        = (const float*)d_in[0];
    const int*   w_codes  = (const int*)d_in[1];
    const int*   am_codes = (const int*)d_in[2];
    const float* am_scale = (const float*)d_in[3];
    const float* am_off   = (const float*)d_in[4];
    const float* bias     = (const float*)d_in[5];
    float* out = (float*)d_out;

    const int M = DIM_M, N = DIM_N, K = DIM_K;

    // workspace: xb (M*K bf16 = 64 MB) | wb (N*K bf16 = 32 MB)
    unsigned short* xb = (unsigned short*)d_ws;
    unsigned short* wb = xb + (size_t)M * K;

    {
        int xcv_blocks = (int)(((size_t)M * K) / 8 / 256);   // 16384
        int wdq_blocks = (int)(((size_t)N * K) / 8 / 256);   // 8192
        prep_kernel<<<xcv_blocks + wdq_blocks, 256, 0, stream>>>(
            x, xb, w_codes, am_codes, am_scale, am_off, wb, xcv_blocks);
    }
    {
        dim3 grid((M / BM) * (N / BN));   // 512 one-dim; XCD swizzle in-kernel
        gemm_bt<<<grid, 512, 0, stream>>>(xb, wb, bias, out, M, N, K);
    }
}

// Round 2
// 484.850 us; speedup vs baseline: 1.1943x; 1.0509x over previous
//
#include <hip/hip_runtime.h>
#include <cstdint>
#include <cstddef>

// Problem dims (fixed by setup_inputs): B=4, S=2048, I=4096, O=4096
#define DIM_M 8192   // B*S
#define DIM_N 4096   // O
#define DIM_K 4096   // I

// GEMM tiling: 256x256 tile, BK=32, 4-deep LDS ring, 1 barrier/tile
#define BM 256
#define BN 256
#define BK 32
#define NT (DIM_K / BK)   // 128 K-tiles

typedef __bf16 bf16x8 __attribute__((ext_vector_type(8)));
typedef float fvec4 __attribute__((ext_vector_type(4)));
typedef int   ivec4 __attribute__((ext_vector_type(4)));
typedef unsigned int uvec4 __attribute__((ext_vector_type(4)));

__device__ __constant__ float NF4_TAB[16] = {
    -1.0f, -0.6961928009986877f, -0.5250730514526367f, -0.39491748809814453f,
    -0.28444138169288635f, -0.18477343022823334f, -0.09105003625154495f, 0.0f,
    0.07958029955625534f, 0.16093020141124725f, 0.24611230194568634f,
    0.33791524171829224f, 0.44070982933044434f, 0.5626170039176941f,
    0.7229568362236023f, 1.0f};

// float -> bf16 bits, round-to-nearest-even (finite inputs only)
__device__ inline unsigned short f2bf(float f) {
    unsigned int u = __builtin_bit_cast(unsigned int, f);
    u += 0x7fffu + ((u >> 16) & 1u);
    return (unsigned short)(u >> 16);
}

// ---------------- fused prep: x fp32->bf16  +  NF4 double-dequant ----------------
// (unchanged — gemm is the attributed change this round)
__global__ void prep_kernel(const float* __restrict__ x, unsigned short* __restrict__ xb,
                            const int* __restrict__ codes,
                            const int* __restrict__ am_codes,
                            const float* __restrict__ am_scale,
                            const float* __restrict__ am_off,
                            unsigned short* __restrict__ wb,
                            int xcv_blocks) {
    if ((int)blockIdx.x < xcv_blocks) {
        size_t base = ((size_t)blockIdx.x * blockDim.x + threadIdx.x) * 8;
        fvec4 a = __builtin_nontemporal_load((const fvec4*)(x + base));
        fvec4 b = __builtin_nontemporal_load((const fvec4*)(x + base + 4));
        unsigned short r[8];
        r[0] = f2bf(a.x); r[1] = f2bf(a.y); r[2] = f2bf(a.z); r[3] = f2bf(a.w);
        r[4] = f2bf(b.x); r[5] = f2bf(b.y); r[6] = f2bf(b.z); r[7] = f2bf(b.w);
        *(uvec4*)(xb + base) = *(const uvec4*)r;
    } else {
        __shared__ float nf4[16];
        if (threadIdx.x < 16) nf4[threadIdx.x] = NF4_TAB[threadIdx.x];
        __syncthreads();
        size_t base = ((size_t)(blockIdx.x - xcv_blocks) * blockDim.x + threadIdx.x) * 8;
        int blk = (int)(base >> 6);
        float absmax = (float)am_codes[blk] * (1.0f / 255.0f) * am_scale[blk >> 8] + am_off[0];
        ivec4 c0 = __builtin_nontemporal_load((const ivec4*)(codes + base));
        ivec4 c1 = __builtin_nontemporal_load((const ivec4*)(codes + base + 4));
        unsigned short r[8];
        r[0] = f2bf(nf4[c0.x & 15] * absmax);
        r[1] = f2bf(nf4[c0.y & 15] * absmax);
        r[2] = f2bf(nf4[c0.z & 15] * absmax);
        r[3] = f2bf(nf4[c0.w & 15] * absmax);
        r[4] = f2bf(nf4[c1.x & 15] * absmax);
        r[5] = f2bf(nf4[c1.y & 15] * absmax);
        r[6] = f2bf(nf4[c1.z & 15] * absmax);
        r[7] = f2bf(nf4[c1.w & 15] * absmax);
        *(uvec4*)(wb + base) = *(const uvec4*)r;
    }
}

// ---------------- 256x256 bf16 MFMA GEMM, 1-barrier/tile, counted vmcnt ----------------
//
// 512 threads = 8 waves (2M x 4N), per-wave 128x64 output, mfma 16x16x32.
// LDS: 4-buffer ring per operand (buf = 256x32 bf16 = 16 KiB) -> 128 KiB.
// Per K-tile t: issue stage loads for t+3 FIRST, then all 12 ds_read_b128,
// then 32 MFMA (compiler fine-grained lgkmcnt handles read->MFMA waits),
// then s_waitcnt vmcnt(8) (tile t+1 landed; t+2,t+3 stay in flight), then ONE
// s_barrier.  Barrier ledger: by the time a wave arrives at the boundary
// barrier, all its LDS reads of tile t are drained (waited before MFMA use)
// and its own tile-(t+1) stage loads are retired (vmcnt) -> after the join,
// buffer (t+1)&3 is fully valid and buffer (t-1)&3 == (t+4)&3 is reusable.
// Main loop unrolled x4 so ring indices/LDS offsets are immediates.
//
// LDS swizzle (both-sides-or-neither, zero conflicts measured): slot (row,c)
// holds global k-chunk c ^ ((row>>1)&3); staging pre-swizzles the per-lane
// GLOBAL source chunk (linear LDS dest, as global_load_lds requires); reads
// apply the same XOR.
__device__ inline void gld_lds16(const void* g, void* l) {
    __builtin_amdgcn_global_load_lds((__attribute__((address_space(1))) void*)g,
                                     (__attribute__((address_space(3))) void*)l,
                                     16, 0, 0);
}

__global__ __launch_bounds__(512, 2) void gemm_bt(const unsigned short* __restrict__ A,
                                                  const unsigned short* __restrict__ B,
                                                  const float* __restrict__ bias,
                                                  float* __restrict__ C,
                                                  int M, int N, int K) {
    __shared__ __attribute__((aligned(16))) unsigned short lA[4][BM * BK];
    __shared__ __attribute__((aligned(16))) unsigned short lB[4][BN * BK];

    const int tid  = threadIdx.x;
    const int wave = tid >> 6;
    const int lane = tid & 63;

    // Bijective XCD swizzle: XCD owns bm in {xcd, xcd+8, ...}; all XCDs walk
    // bn 0..15 in lockstep (A panels L2-hot per XCD, B panels L3-shared).
    const int orig = (int)blockIdx.x;
    const int xcd = orig & 7;
    const int idx = orig >> 3;                 // 0..63
    const int bm = ((idx >> 4) << 3) + xcd;    // 0..31
    const int bn = idx & 15;                   // 0..15

    const int wm = (wave >> 2) * 128;
    const int wn = (wave & 3) * 64;

    // Staging: thread t owns 16B slots t and t+512 (rows tid>>2 and +128, same
    // chunk col); source chunk pre-swizzled: gch = (t&3) ^ ((t>>3)&3).
    const int srow = tid >> 2;
    const int gch  = (tid & 3) ^ ((tid >> 3) & 3);
    const unsigned short* sA0 = A + (size_t)(bm * BM + srow) * K + gch * 8;
    const unsigned short* sA1 = sA0 + (size_t)128 * K;
    const unsigned short* sB0 = B + (size_t)(bn * BN + srow) * K + gch * 8;
    const unsigned short* sB1 = sB0 + (size_t)128 * K;

    // Fragment read offsets: row = w? + f*16 + (lane&15), k-chunk = lane>>4,
    // stored at chunk (lane>>4) ^ ((lane>>1)&3)  (swizzle dep only on row&7).
    const int cslot = (lane >> 4) ^ ((lane >> 1) & 3);
    const int aoff = (wm + (lane & 15)) * BK + cslot * 8;
    const int boff = (wn + (lane & 15)) * BK + cslot * 8;

    fvec4 acc[8][4];
#pragma unroll
    for (int m = 0; m < 8; ++m)
#pragma unroll
        for (int n = 0; n < 4; ++n)
#pragma unroll
            for (int r = 0; r < 4; ++r) acc[m][n][r] = 0.0f;

    // ---- prologue: issue tiles 0,1,2 (12 loads/thread); tile 0 ready at vmcnt(8) ----
#pragma unroll
    for (int pt = 0; pt < 3; ++pt) {
        const int kb = pt * BK;
        gld_lds16(sA0 + kb, &lA[pt][tid * 8]);
        gld_lds16(sA1 + kb, &lA[pt][(tid + 512) * 8]);
        gld_lds16(sB0 + kb, &lB[pt][tid * 8]);
        gld_lds16(sB1 + kb, &lB[pt][(tid + 512) * 8]);
    }
    asm volatile("s_waitcnt vmcnt(8)" ::: "memory");
    __builtin_amdgcn_s_barrier();

    // ---- main loop: 31 iterations x 4 tiles, ring indices as immediates ----
#define TILE_MAIN(J)                                                                   \
    do {                                                                               \
        constexpr int BUF = (J) & 3;                                                   \
        constexpr int NBUF = (BUF + 3) & 3;                                            \
        gld_lds16(pA0 + (J) * BK, &lA[NBUF][tid * 8]);                                 \
        gld_lds16(pA1 + (J) * BK, &lA[NBUF][(tid + 512) * 8]);                         \
        gld_lds16(pB0 + (J) * BK, &lB[NBUF][tid * 8]);                                 \
        gld_lds16(pB1 + (J) * BK, &lB[NBUF][(tid + 512) * 8]);                         \
        bf16x8 a0[4], a1[4], bv[4];                                                    \
        _Pragma("unroll") for (int m = 0; m < 4; ++m)                                  \
            a0[m] = *(const bf16x8*)(&lA[BUF][0] + aoff + m * 512);                    \
        _Pragma("unroll") for (int n = 0; n < 4; ++n)                                  \
            bv[n] = *(const bf16x8*)(&lB[BUF][0] + boff + n * 512);                    \
        _Pragma("unroll") for (int m = 0; m < 4; ++m)                                  \
            a1[m] = *(const bf16x8*)(&lA[BUF][0] + aoff + (m + 4) * 512);              \
        __builtin_amdgcn_s_setprio(1);                                                 \
        _Pragma("unroll") for (int m = 0; m < 4; ++m)                                  \
            _Pragma("unroll") for (int n = 0; n < 4; ++n)                              \
                acc[m][n] = __builtin_amdgcn_mfma_f32_16x16x32_bf16(a0[m], bv[n], acc[m][n], 0, 0, 0); \
        _Pragma("unroll") for (int m = 0; m < 4; ++m)                                  \
            _Pragma("unroll") for (int n = 0; n < 4; ++n)                              \
                acc[m + 4][n] = __builtin_amdgcn_mfma_f32_16x16x32_bf16(a1[m], bv[n], acc[m + 4][n], 0, 0, 0); \
        __builtin_amdgcn_s_setprio(0);                                                 \
        asm volatile("s_waitcnt vmcnt(8)" ::: "memory");                               \
        __builtin_amdgcn_s_barrier();                                                  \
    } while (0)

    {
        const unsigned short* pA0 = sA0 + 3 * BK;
        const unsigned short* pA1 = sA1 + 3 * BK;
        const unsigned short* pB0 = sB0 + 3 * BK;
        const unsigned short* pB1 = sB1 + 3 * BK;
        for (int t0 = 0; t0 < NT - 4; t0 += 4) {   // t = 0..123, stages tiles 3..126
            TILE_MAIN(0);
            TILE_MAIN(1);
            TILE_MAIN(2);
            TILE_MAIN(3);
            pA0 += 4 * BK; pA1 += 4 * BK; pB0 += 4 * BK; pB1 += 4 * BK;
        }
    }

    // ---- tail: tiles 124..127 (stage 127 once; vmcnt ladder 8 -> 4 -> 0) ----
    for (int t = NT - 4; t < NT; ++t) {
        const int b = t & 3;
        if (t + 3 < NT) {   // t == 124 only
            const size_t kb = (size_t)(t + 3) * BK;
            gld_lds16(sA0 + kb, &lA[(b + 3) & 3][tid * 8]);
            gld_lds16(sA1 + kb, &lA[(b + 3) & 3][(tid + 512) * 8]);
            gld_lds16(sB0 + kb, &lB[(b + 3) & 3][tid * 8]);
            gld_lds16(sB1 + kb, &lB[(b + 3) & 3][(tid + 512) * 8]);
        }
        bf16x8 a0[4], a1[4], bv[4];
#pragma unroll
        for (int m = 0; m < 4; ++m) a0[m] = *(const bf16x8*)(&lA[b][0] + aoff + m * 512);
#pragma unroll
        for (int n = 0; n < 4; ++n) bv[n] = *(const bf16x8*)(&lB[b][0] + boff + n * 512);
#pragma unroll
        for (int m = 0; m < 4; ++m) a1[m] = *(const bf16x8*)(&lA[b][0] + aoff + (m + 4) * 512);
        __builtin_amdgcn_s_setprio(1);
#pragma unroll
        for (int m = 0; m < 4; ++m)
#pragma unroll
            for (int n = 0; n < 4; ++n)
                acc[m][n] = __builtin_amdgcn_mfma_f32_16x16x32_bf16(a0[m], bv[n], acc[m][n], 0, 0, 0);
#pragma unroll
        for (int m = 0; m < 4; ++m)
#pragma unroll
            for (int n = 0; n < 4; ++n)
                acc[m + 4][n] = __builtin_amdgcn_mfma_f32_16x16x32_bf16(a1[m], bv[n], acc[m + 4][n], 0, 0, 0);
        __builtin_amdgcn_s_setprio(0);
        if (t == NT - 4)      { asm volatile("s_waitcnt vmcnt(8)" ::: "memory"); }
        else if (t == NT - 3) { asm volatile("s_waitcnt vmcnt(4)" ::: "memory"); }
        else if (t == NT - 2) { asm volatile("s_waitcnt vmcnt(0)" ::: "memory"); }
        if (t < NT - 1) __builtin_amdgcn_s_barrier();
    }

    // ---- epilogue: C/D 16x16 layout col = lane&15, row = (lane>>4)*4 + r ----
    const int col0 = bn * BN + wn + (lane & 15);
    const int row0 = bm * BM + wm + ((lane >> 4) << 2);
#pragma unroll
    for (int n = 0; n < 4; ++n) {
        const float bvs = bias[col0 + n * 16];
#pragma unroll
        for (int m = 0; m < 8; ++m) {
            float* cp = C + (size_t)(row0 + m * 16) * N + col0 + n * 16;
#pragma unroll
            for (int r = 0; r < 4; ++r)
                __builtin_nontemporal_store(acc[m][n][r] + bvs, cp + (size_t)r * N);
        }
    }
}

extern "C" void kernel_launch(void* const* d_in, const int* in_sizes, int n_in,
                              void* d_out, int out_size, void* d_ws, size_t ws_size,
                              hipStream_t stream) {
    const float* x        = (const float*)d_in[0];
    const int*   w_codes  = (const int*)d_in[1];
    const int*   am_codes = (const int*)d_in[2];
    const float* am_scale = (const float*)d_in[3];
    const float* am_off   = (const float*)d_in[4];
    const float* bias     = (const float*)d_in[5];
    float* out = (float*)d_out;

    const int M = DIM_M, N = DIM_N, K = DIM_K;

    // workspace: xb (M*K bf16 = 64 MB) | wb (N*K bf16 = 32 MB)
    unsigned short* xb = (unsigned short*)d_ws;
    unsigned short* wb = xb + (size_t)M * K;

    {
        int xcv_blocks = (int)(((size_t)M * K) / 8 / 256);   // 16384
        int wdq_blocks = (int)(((size_t)N * K) / 8 / 256);   // 8192
        prep_kernel<<<xcv_blocks + wdq_blocks, 256, 0, stream>>>(
            x, xb, w_codes, am_codes, am_scale, am_off, wb, xcv_blocks);
    }
    {
        dim3 grid((M / BM) * (N / BN));   // 512 one-dim; XCD swizzle in-kernel
        gemm_bt<<<grid, 512, 0, stream>>>(xb, wb, bias, out, M, N, K);
    }
}